// Round 1
// baseline (1170.475 us; speedup 1.0000x reference)
//
#include <hip/hip_runtime.h>
#include <float.h>
#include <math.h>

// Problem constants (fixed by the reference file)
#define B_  8
#define H_  8
#define L_  2048
#define D_  64
#define NS  40          // num selected = min(5*ceil(ln(2048)), 2048) = 40
#define BH  (B_*H_)
#define SCALE 0.125f    // d^-0.5 = 1/8

// ---------------------------------------------------------------------------
// K1: sparsity measure.  One 64-lane wave per query i (lane = d).
// measure[bh,i] = max_j dot(q[i], k[ridx[i,j]]) - (sum_j dot)/L
// ---------------------------------------------------------------------------
__global__ __launch_bounds__(256) void measure_kernel(
    const float* __restrict__ q, const float* __restrict__ k,
    const int* __restrict__ ridx, float* __restrict__ measure)
{
    int wave = threadIdx.x >> 6;          // 0..3, 4 queries per block
    int lane = threadIdx.x & 63;          // d
    int qid  = blockIdx.x * 4 + wave;     // global query id in [0, BH*L)
    int bh   = qid >> 11;                 // / L_
    int i    = qid & (L_ - 1);

    float qv = q[((size_t)bh * L_ + i) * D_ + lane];
    const int*   ri    = ridx + (size_t)i * NS;
    const float* kbase = k + (size_t)bh * L_ * D_;

    float maxv = -FLT_MAX, sumv = 0.f;
    for (int j = 0; j < NS; ++j) {
        int r = ri[j];                                    // wave-uniform broadcast
        float p = qv * kbase[(size_t)r * D_ + lane];      // coalesced 256B row
        #pragma unroll
        for (int off = 32; off; off >>= 1) p += __shfl_xor(p, off, 64);
        maxv = fmaxf(maxv, p);
        sumv += p;
    }
    if (lane == 0)
        measure[(size_t)bh * L_ + i] = maxv - sumv * (1.0f / (float)L_);
}

// ---------------------------------------------------------------------------
// K2: top-NS per (b,h).  Matches lax.top_k ordering: value desc, index asc.
// ---------------------------------------------------------------------------
__global__ __launch_bounds__(256) void topk_kernel(
    const float* __restrict__ measure, int* __restrict__ idxOut)
{
    __shared__ float sm[L_];
    __shared__ float rv[256];
    __shared__ int   rix[256];
    int bh = blockIdx.x;
    const float* m = measure + (size_t)bh * L_;
    for (int t = threadIdx.x; t < L_; t += 256) sm[t] = m[t];
    __syncthreads();

    for (int r = 0; r < NS; ++r) {
        float bv = -FLT_MAX; int bi = 0x7fffffff;
        for (int t = threadIdx.x; t < L_; t += 256) {
            float v = sm[t];
            if (v > bv || (v == bv && t < bi)) { bv = v; bi = t; }
        }
        rv[threadIdx.x] = bv; rix[threadIdx.x] = bi;
        __syncthreads();
        for (int s = 128; s; s >>= 1) {
            if (threadIdx.x < s) {
                float ov = rv[threadIdx.x + s]; int oi = rix[threadIdx.x + s];
                if (ov > rv[threadIdx.x] ||
                    (ov == rv[threadIdx.x] && oi < rix[threadIdx.x])) {
                    rv[threadIdx.x] = ov; rix[threadIdx.x] = oi;
                }
            }
            __syncthreads();
        }
        if (threadIdx.x == 0) {
            idxOut[bh * NS + r] = rix[0];
            sm[rix[0]] = -FLT_MAX;          // remove winner
        }
        __syncthreads();
    }
}

// ---------------------------------------------------------------------------
// K3: cumsum(v) along L into out.  One block (1024 thr) per (b,h):
// 16 chunks x 64 d-lanes; chunk-sum -> exclusive scan -> rescan+write.
// ---------------------------------------------------------------------------
__global__ __launch_bounds__(1024) void cumsum_kernel(
    const float* __restrict__ v, float* __restrict__ out)
{
    __shared__ float csum[16][D_];
    int bh = blockIdx.x;
    int d  = threadIdx.x & 63;
    int c  = threadIdx.x >> 6;            // 0..15, chunk of 128 rows
    const float* vb = v   + (size_t)bh * L_ * D_;
    float*       ob = out + (size_t)bh * L_ * D_;
    int r0 = c * 128;

    float s = 0.f;
    for (int r = r0; r < r0 + 128; ++r) s += vb[(size_t)r * D_ + d];
    csum[c][d] = s;
    __syncthreads();
    if (c == 0) {                         // exclusive scan over 16 chunks per d
        float run = 0.f;
        for (int cc = 0; cc < 16; ++cc) {
            float t = csum[cc][d];
            csum[cc][d] = run;
            run += t;
        }
    }
    __syncthreads();
    float run = csum[c][d];
    for (int r = r0; r < r0 + 128; ++r) {
        run += vb[(size_t)r * D_ + d];
        ob[(size_t)r * D_ + d] = run;     // coalesced: d contiguous
    }
}

// ---------------------------------------------------------------------------
// K4: full attention for the NS selected queries.  One block per (bh, rank).
// Causal mask j <= qrow; writes attn row (zeros beyond mask) and overwrites
// out[bh, qrow, :] with attn @ v.
// ---------------------------------------------------------------------------
__global__ __launch_bounds__(256) void attn_kernel(
    const float* __restrict__ q, const float* __restrict__ k,
    const float* __restrict__ v, const int* __restrict__ idxSel,
    float* __restrict__ out, float* __restrict__ attnOut)
{
    __shared__ float qs[D_];
    __shared__ float sc[L_];
    __shared__ float red[256];
    __shared__ float pv[4][D_];

    int bh = blockIdx.x / NS;
    int r  = blockIdx.x % NS;
    int qrow = idxSel[bh * NS + r];
    const float* kb = k + (size_t)bh * L_ * D_;
    const float* vb = v + (size_t)bh * L_ * D_;

    if (threadIdx.x < D_)
        qs[threadIdx.x] = q[((size_t)bh * L_ + qrow) * D_ + threadIdx.x];
    __syncthreads();

    int wave = threadIdx.x >> 6, lane = threadIdx.x & 63;
    float qv = qs[lane];

    // scores: wave w handles rows j = w, w+4, ... (skip masked rows entirely)
    for (int j = wave; j < L_; j += 4) {
        float s;
        if (j <= qrow) {
            float p = qv * kb[(size_t)j * D_ + lane];
            #pragma unroll
            for (int off = 32; off; off >>= 1) p += __shfl_xor(p, off, 64);
            s = p * SCALE;
        } else {
            s = -FLT_MAX;
        }
        if (lane == 0) sc[j] = s;
    }
    __syncthreads();

    // block max over valid scores
    float m = -FLT_MAX;
    for (int t = threadIdx.x; t < L_; t += 256) m = fmaxf(m, sc[t]);
    red[threadIdx.x] = m; __syncthreads();
    for (int s = 128; s; s >>= 1) {
        if (threadIdx.x < s) red[threadIdx.x] = fmaxf(red[threadIdx.x], red[threadIdx.x + s]);
        __syncthreads();
    }
    m = red[0];
    __syncthreads();

    // exp + sum
    float psum = 0.f;
    for (int t = threadIdx.x; t < L_; t += 256) {
        float e = (t <= qrow) ? expf(sc[t] - m) : 0.f;
        sc[t] = e; psum += e;
    }
    red[threadIdx.x] = psum; __syncthreads();
    for (int s = 128; s; s >>= 1) {
        if (threadIdx.x < s) red[threadIdx.x] += red[threadIdx.x + s];
        __syncthreads();
    }
    float inv = 1.f / red[0];
    __syncthreads();

    // normalize in LDS + write attn row (coalesced)
    float* arow = attnOut + ((size_t)bh * NS + r) * L_;
    for (int t = threadIdx.x; t < L_; t += 256) {
        float w = sc[t] * inv;
        sc[t] = w;
        arow[t] = w;
    }
    __syncthreads();

    // out_sel[d] = sum_j w_j * v[j,d]; thread (c=wave, d=lane), j in c-th quarter
    float acc = 0.f;
    int c = wave, d = lane;
    int jhi = (c + 1) * 512;
    for (int j = c * 512; j < jhi && j <= qrow; ++j)
        acc += sc[j] * vb[(size_t)j * D_ + d];   // coalesced across d
    pv[c][d] = acc;
    __syncthreads();
    if (threadIdx.x < D_) {
        float t = pv[0][threadIdx.x] + pv[1][threadIdx.x]
                + pv[2][threadIdx.x] + pv[3][threadIdx.x];
        out[((size_t)bh * L_ + qrow) * D_ + threadIdx.x] = t;
    }
}

// ---------------------------------------------------------------------------
extern "C" void kernel_launch(void* const* d_in, const int* in_sizes, int n_in,
                              void* d_out, int out_size, void* d_ws, size_t ws_size,
                              hipStream_t stream) {
    const float* q    = (const float*)d_in[0];
    const float* k    = (const float*)d_in[1];
    const float* v    = (const float*)d_in[2];
    const int*   ridx = (const int*)d_in[3];

    float* out     = (float*)d_out;                        // (B,H,L,D)
    float* attnOut = out + (size_t)BH * L_ * D_;           // (B,H,NS,L)

    float* measure = (float*)d_ws;                                         // BH*L floats
    int*   idxSel  = (int*)((char*)d_ws + (size_t)BH * L_ * sizeof(float)); // BH*NS ints

    measure_kernel<<<BH * L_ / 4, 256, 0, stream>>>(q, k, ridx, measure);
    topk_kernel  <<<BH,           256, 0, stream>>>(measure, idxSel);
    cumsum_kernel<<<BH,          1024, 0, stream>>>(v, out);
    attn_kernel  <<<BH * NS,      256, 0, stream>>>(q, k, v, idxSel, out, attnOut);
}

// Round 2
// 507.669 us; speedup vs baseline: 2.3056x; 2.3056x over previous
//
#include <hip/hip_runtime.h>
#include <float.h>
#include <math.h>

#define B_  8
#define H_  8
#define L_  2048
#define D_  64
#define NS  40          // num selected = min(5*ceil(ln(2048)), 2048) = 40
#define BH  (B_*H_)
#define SCALE 0.125f    // d^-0.5

// ---------------------------------------------------------------------------
// K1: sparsity measure.  One wave per query, lane = sampled-k index j (<40).
// Each lane computes a full 64-wide dot in registers (16 float4 gathers from
// L2-resident k), then ONE combined max+sum wave reduction.
// ---------------------------------------------------------------------------
__global__ __launch_bounds__(256) void measure_kernel(
    const float* __restrict__ q, const float* __restrict__ k,
    const int* __restrict__ ridx, float* __restrict__ measure)
{
    __shared__ float4 qs4[4][16];       // 4 q rows per block
    int wave = threadIdx.x >> 6, lane = threadIdx.x & 63;
    int qid0 = blockIdx.x * 4;
    ((float*)qs4)[threadIdx.x] = q[(size_t)(qid0 + wave) * D_ + lane]; // coalesced
    __syncthreads();

    int qid = qid0 + wave;
    int bh  = qid >> 11;                // / L_
    int i   = qid & (L_ - 1);

    int r = 0;
    if (lane < NS) r = ridx[i * NS + lane];     // coalesced 160B
    const float4* krow = (const float4*)(k + ((size_t)bh * L_ + r) * D_);
    const float4* qr   = qs4[wave];

    float acc = 0.f;
    #pragma unroll
    for (int g = 0; g < 16; ++g) {
        float4 kk = krow[g];            // f4 gather, L2-resident
        float4 qq = qr[g];              // LDS broadcast
        acc += qq.x*kk.x + qq.y*kk.y + qq.z*kk.z + qq.w*kk.w;
    }
    float mx = (lane < NS) ? acc : -FLT_MAX;
    float sm = (lane < NS) ? acc : 0.f;
    #pragma unroll
    for (int off = 32; off; off >>= 1) {
        mx = fmaxf(mx, __shfl_xor(mx, off, 64));
        sm += __shfl_xor(sm, off, 64);
    }
    if (lane == 0)
        measure[(size_t)bh * L_ + i] = mx - sm * (1.0f / (float)L_);
}

// ---------------------------------------------------------------------------
// K2: top-NS per (b,h), register-resident.  Each thread owns 8 contiguous
// elements; per round: 6-step wave reduce + 4-way LDS merge; only the
// winner's owner rescans its 8 values.  Ties: lower index (lax.top_k).
// ---------------------------------------------------------------------------
__global__ __launch_bounds__(256) void topk_kernel(
    const float* __restrict__ measure, int* __restrict__ idxOut)
{
    __shared__ float wv[4]; __shared__ int wi[4];
    __shared__ float bvS;   __shared__ int biS;
    int bh = blockIdx.x, t = threadIdx.x;
    const float4* m4 = (const float4*)(measure + (size_t)bh * L_);
    float vals[8];
    float4 a = m4[t*2], b = m4[t*2 + 1];
    vals[0]=a.x; vals[1]=a.y; vals[2]=a.z; vals[3]=a.w;
    vals[4]=b.x; vals[5]=b.y; vals[6]=b.z; vals[7]=b.w;

    float lv = -FLT_MAX; int li = t*8;
    #pragma unroll
    for (int e = 0; e < 8; ++e) if (vals[e] > lv) { lv = vals[e]; li = t*8 + e; }

    int lane = t & 63, w = t >> 6;
    for (int r = 0; r < NS; ++r) {
        float v = lv; int idx = li;
        #pragma unroll
        for (int off = 32; off; off >>= 1) {
            float ov = __shfl_xor(v, off, 64);
            int   oi = __shfl_xor(idx, off, 64);
            if (ov > v || (ov == v && oi < idx)) { v = ov; idx = oi; }
        }
        if (lane == 0) { wv[w] = v; wi[w] = idx; }
        __syncthreads();
        if (t == 0) {
            float bv = wv[0]; int bi = wi[0];
            #pragma unroll
            for (int ww = 1; ww < 4; ++ww)
                if (wv[ww] > bv || (wv[ww] == bv && wi[ww] < bi)) { bv = wv[ww]; bi = wi[ww]; }
            bvS = bv; biS = bi;
            idxOut[bh * NS + r] = bi;
        }
        __syncthreads();
        int bi = biS;
        if ((bi >> 3) == t) {
            #pragma unroll
            for (int e = 0; e < 8; ++e) if ((bi & 7) == e) vals[e] = -FLT_MAX;
            lv = -FLT_MAX; li = t*8;
            #pragma unroll
            for (int e = 0; e < 8; ++e) if (vals[e] > lv) { lv = vals[e]; li = t*8 + e; }
        }
        __syncthreads();
    }
}

// ---------------------------------------------------------------------------
// K3: cumsum(v) along L, two passes, 1024 blocks each.
// Pass1: 128-row chunk partial sums.  Pass2: scan + write.
// ---------------------------------------------------------------------------
__global__ __launch_bounds__(256) void cumsum_p1(
    const float* __restrict__ v, float4* __restrict__ vpart)
{
    __shared__ float4 part[16][16];
    int bh = blockIdx.x >> 4, c = blockIdx.x & 15;
    int d4 = threadIdx.x & 15, sub = threadIdx.x >> 4;
    const float4* vb = (const float4*)(v + (size_t)bh * L_ * D_);
    int r0 = c*128 + sub*8;
    float4 s = make_float4(0,0,0,0);
    #pragma unroll
    for (int r = 0; r < 8; ++r) {
        float4 x = vb[(r0 + r)*16 + d4];
        s.x += x.x; s.y += x.y; s.z += x.z; s.w += x.w;
    }
    part[sub][d4] = s;
    __syncthreads();
    if (sub == 0) {
        float4 tot = part[0][d4];
        #pragma unroll
        for (int ss = 1; ss < 16; ++ss) {
            float4 x = part[ss][d4];
            tot.x += x.x; tot.y += x.y; tot.z += x.z; tot.w += x.w;
        }
        vpart[(bh*16 + c)*16 + d4] = tot;
    }
}

__global__ __launch_bounds__(256) void cumsum_p2(
    const float* __restrict__ v, const float4* __restrict__ vpart,
    float* __restrict__ out)
{
    __shared__ float4 part[16][16];
    int bh = blockIdx.x >> 4, c = blockIdx.x & 15;
    int d4 = threadIdx.x & 15, sub = threadIdx.x >> 4;
    const float4* vb = (const float4*)(v + (size_t)bh * L_ * D_);
    float4*       ob = (float4*)(out + (size_t)bh * L_ * D_);
    int r0 = c*128 + sub*8;
    float4 s = make_float4(0,0,0,0);
    #pragma unroll
    for (int r = 0; r < 8; ++r) {
        float4 x = vb[(r0 + r)*16 + d4];
        s.x += x.x; s.y += x.y; s.z += x.z; s.w += x.w;
    }
    part[sub][d4] = s;
    float4 run = make_float4(0,0,0,0);
    for (int cc = 0; cc < c; ++cc) {                  // cross-chunk prefix
        float4 x = vpart[(bh*16 + cc)*16 + d4];
        run.x += x.x; run.y += x.y; run.z += x.z; run.w += x.w;
    }
    __syncthreads();
    #pragma unroll
    for (int ss = 0; ss < 16; ++ss) {                 // within-chunk sub prefix
        if (ss < sub) {
            float4 x = part[ss][d4];
            run.x += x.x; run.y += x.y; run.z += x.z; run.w += x.w;
        }
    }
    #pragma unroll
    for (int r = 0; r < 8; ++r) {
        float4 x = vb[(r0 + r)*16 + d4];
        run.x += x.x; run.y += x.y; run.z += x.z; run.w += x.w;
        ob[(r0 + r)*16 + d4] = run;
    }
}

// ---------------------------------------------------------------------------
// K4a: raw scores for selected queries.  Block = (bh, group of 4 ranks),
// grid 640.  k staged per 128-row chunk in LDS (transposed f4 layout,
// +1 f4 pad -> dense conflict-free b128 reads).  q in registers.
// Writes raw (scaled) scores into the attn output buffer.
// ---------------------------------------------------------------------------
__global__ __launch_bounds__(256) void scores_kernel(
    const float* __restrict__ q, const float* __restrict__ k,
    const int* __restrict__ idxSel, float* __restrict__ attn)
{
    __shared__ float4 kbuf[16 * 129];   // [g][j], stride 129 f4
    __shared__ int qr4[4];
    int bh = blockIdx.x / 10, grp = blockIdx.x % 10;
    int qi = threadIdx.x >> 6, sub = threadIdx.x & 63;
    int rank = grp*4 + qi;
    int qrow = idxSel[bh*NS + rank];
    if (sub == 0) qr4[qi] = qrow;
    __syncthreads();
    int maxq = max(max(qr4[0], qr4[1]), max(qr4[2], qr4[3]));
    int cmax = maxq >> 7;

    const float4* qrp = (const float4*)(q + ((size_t)bh * L_ + qrow) * D_);
    float4 qreg[16];
    #pragma unroll
    for (int g = 0; g < 16; ++g) qreg[g] = qrp[g];    // wave-uniform

    const float4* kb = (const float4*)(k + (size_t)bh * L_ * D_);
    float* arow = attn + (size_t)(bh*NS + rank) * L_;

    for (int c = 0; c <= cmax; ++c) {
        __syncthreads();                               // kbuf reuse guard
        int j0 = c * 128;
        #pragma unroll
        for (int it = 0; it < 8; ++it) {               // coalesced stage
            int fi = threadIdx.x + 256*it;
            int g = fi & 15, j = fi >> 4;
            kbuf[g*129 + j] = kb[(size_t)(j0 + j)*16 + g];
        }
        __syncthreads();
        float acc0 = 0.f, acc1 = 0.f;
        #pragma unroll
        for (int g = 0; g < 16; ++g) {
            float4 k0 = kbuf[g*129 + sub];             // dense b128
            float4 k1 = kbuf[g*129 + sub + 64];
            float4 qq = qreg[g];
            acc0 += qq.x*k0.x + qq.y*k0.y + qq.z*k0.z + qq.w*k0.w;
            acc1 += qq.x*k1.x + qq.y*k1.y + qq.z*k1.z + qq.w*k1.w;
        }
        arow[j0 + sub]      = acc0 * SCALE;            // coalesced
        arow[j0 + sub + 64] = acc1 * SCALE;
    }
}

// ---------------------------------------------------------------------------
// K4b: softmax in-place over each attn row (causal, zeros beyond qrow).
// Row held in registers (8 floats/thread).
// ---------------------------------------------------------------------------
__global__ __launch_bounds__(256) void softmax_kernel(
    const int* __restrict__ idxSel, float* __restrict__ attn)
{
    __shared__ float red[4];
    int bh = blockIdx.x / NS, r = blockIdx.x % NS;
    int qrow = idxSel[bh*NS + r];
    float4* arow = (float4*)(attn + (size_t)(bh*NS + r) * L_);
    int t = threadIdx.x, lane = t & 63, w = t >> 6;

    float4 x0 = arow[t], x1 = arow[t + 256];
    int j0 = 4*t, j1 = 4*(t + 256);
    float v0[4] = {x0.x, x0.y, x0.z, x0.w};
    float v1[4] = {x1.x, x1.y, x1.z, x1.w};

    float mx = -FLT_MAX;
    #pragma unroll
    for (int e = 0; e < 4; ++e) {
        if (j0 + e <= qrow) mx = fmaxf(mx, v0[e]);
        if (j1 + e <= qrow) mx = fmaxf(mx, v1[e]);
    }
    #pragma unroll
    for (int off = 32; off; off >>= 1) mx = fmaxf(mx, __shfl_xor(mx, off, 64));
    if (lane == 0) red[w] = mx;
    __syncthreads();
    mx = fmaxf(fmaxf(red[0], red[1]), fmaxf(red[2], red[3]));
    __syncthreads();

    float sum = 0.f;
    #pragma unroll
    for (int e = 0; e < 4; ++e) {
        v0[e] = (j0 + e <= qrow) ? __expf(v0[e] - mx) : 0.f;
        v1[e] = (j1 + e <= qrow) ? __expf(v1[e] - mx) : 0.f;
        sum += v0[e] + v1[e];
    }
    #pragma unroll
    for (int off = 32; off; off >>= 1) sum += __shfl_xor(sum, off, 64);
    if (lane == 0) red[w] = sum;
    __syncthreads();
    float inv = 1.f / (red[0] + red[1] + red[2] + red[3]);

    arow[t]       = make_float4(v0[0]*inv, v0[1]*inv, v0[2]*inv, v0[3]*inv);
    arow[t + 256] = make_float4(v1[0]*inv, v1[1]*inv, v1[2]*inv, v1[3]*inv);
}

// ---------------------------------------------------------------------------
// K4c: out[bh, qrow, :] = attn_row @ v.  Weights staged in padded LDS
// (conflict-free broadcast), v read as coalesced float4.
// ---------------------------------------------------------------------------
__global__ __launch_bounds__(256) void pv_kernel(
    const float* __restrict__ v, const int* __restrict__ idxSel,
    const float* __restrict__ attn, float* __restrict__ out)
{
    __shared__ float wl[L_ + 64];       // index j + 4*(j>>7)
    __shared__ float4 part[16][16];
    int bh = blockIdx.x / NS, r = blockIdx.x % NS;
    int qrow = idxSel[bh*NS + r];
    const float4* ar = (const float4*)(attn + (size_t)(bh*NS + r) * L_);
    int t = threadIdx.x;

    #pragma unroll
    for (int it = 0; it < 2; ++it) {
        int f = t + 256*it;
        float4 x = ar[f];
        int j = 4*f;
        *((float4*)&wl[j + 4*(j >> 7)]) = x;
    }
    __syncthreads();

    int d4 = t & 15, seg = t >> 4;
    const float4* vb = (const float4*)(v + (size_t)bh * L_ * D_);
    float4 acc = make_float4(0,0,0,0);
    int jlo = seg*128, jhi = min(jlo + 127, qrow);
    for (int j = jlo; j <= jhi; ++j) {
        float wgt = wl[j + 4*(j >> 7)];
        float4 x = vb[(size_t)j*16 + d4];
        acc.x += wgt*x.x; acc.y += wgt*x.y; acc.z += wgt*x.z; acc.w += wgt*x.w;
    }
    part[seg][d4] = acc;
    __syncthreads();
    for (int s2 = 8; s2; s2 >>= 1) {
        if (seg < s2) {
            float4 o = part[seg + s2][d4];
            acc.x += o.x; acc.y += o.y; acc.z += o.z; acc.w += o.w;
            part[seg][d4] = acc;
        }
        __syncthreads();
    }
    if (seg == 0) {
        float4* orow = (float4*)(out + ((size_t)bh * L_ + qrow) * D_);
        orow[d4] = acc;
    }
}

// ---------------------------------------------------------------------------
extern "C" void kernel_launch(void* const* d_in, const int* in_sizes, int n_in,
                              void* d_out, int out_size, void* d_ws, size_t ws_size,
                              hipStream_t stream) {
    const float* q    = (const float*)d_in[0];
    const float* k    = (const float*)d_in[1];
    const float* v    = (const float*)d_in[2];
    const int*   ridx = (const int*)d_in[3];

    float* out     = (float*)d_out;                    // (B,H,L,D)
    float* attnOut = out + (size_t)BH * L_ * D_;       // (B,H,NS,L)

    float*  measure = (float*)d_ws;                                          // BH*L floats
    int*    idxSel  = (int*)((char*)d_ws + (size_t)BH * L_ * sizeof(float)); // BH*NS ints
    float4* vpart   = (float4*)d_ws;   // aliases measure: only used AFTER topk

    measure_kernel<<<BH * L_ / 4, 256, 0, stream>>>(q, k, ridx, measure);
    topk_kernel   <<<BH,          256, 0, stream>>>(measure, idxSel);
    cumsum_p1     <<<BH * 16,     256, 0, stream>>>(v, vpart);
    cumsum_p2     <<<BH * 16,     256, 0, stream>>>(v, vpart, out);
    scores_kernel <<<BH * 10,     256, 0, stream>>>(q, k, idxSel, attnOut);
    softmax_kernel<<<BH * NS,     256, 0, stream>>>(idxSel, attnOut);
    pv_kernel     <<<BH * NS,     256, 0, stream>>>(v, idxSel, attnOut, out);
}

// Round 3
// 383.679 us; speedup vs baseline: 3.0507x; 1.3232x over previous
//
#include <hip/hip_runtime.h>
#include <float.h>
#include <math.h>

#define B_  8
#define H_  8
#define L_  2048
#define D_  64
#define NS  40          // num selected = min(5*ceil(ln(2048)), 2048) = 40
#define BH  (B_*H_)
#define SCALE 0.125f    // d^-0.5

// ---------------------------------------------------------------------------
// K1: sparsity measure.  One wave per query.  Quarter-wave (16 lanes x f4)
// reads one k row per gather instruction -> 4 rows / 16 cache lines per
// instruction (vs 40 lines in the lane-per-row layout).  10 passes cover
// the 40 samples; intra-quarter shuffle reduce; cross-quarter combine.
// ---------------------------------------------------------------------------
__global__ __launch_bounds__(256) void measure_kernel(
    const float* __restrict__ q, const float* __restrict__ k,
    const int* __restrict__ ridx, float* __restrict__ measure)
{
    int wave = threadIdx.x >> 6, lane = threadIdx.x & 63;
    int qid = blockIdx.x * 4 + wave;
    int bh  = qid >> 11;                 // / L_
    int i   = qid & (L_ - 1);
    int qj  = lane >> 4;                 // quarter id 0..3
    int d4  = lane & 15;                 // float4 index within row

    // per-lane sample index (lanes >= NS replicate the last index)
    int rs = ridx[i * NS + (lane < NS ? lane : NS - 1)];

    const float4* kb = (const float4*)(k + (size_t)bh * L_ * D_);
    float4 qq = ((const float4*)(q + ((size_t)bh * L_ + i) * D_))[d4];

    float mx = -FLT_MAX, sm = 0.f;
    #pragma unroll
    for (int p = 0; p < 10; ++p) {
        int j = p * 4 + qj;                      // sample handled by my quarter
        int r = __shfl(rs, j, 64);
        float4 kk = kb[(size_t)r * 16 + d4];     // 16 lanes cover the row
        float pp = qq.x*kk.x + qq.y*kk.y + qq.z*kk.z + qq.w*kk.w;
        pp += __shfl_xor(pp, 1, 64);
        pp += __shfl_xor(pp, 2, 64);
        pp += __shfl_xor(pp, 4, 64);
        pp += __shfl_xor(pp, 8, 64);             // all 16 lanes: dot(q, k[r])
        mx = fmaxf(mx, pp);
        sm += pp;
    }
    // combine the 4 quarters (each holds stats over its 10 samples)
    mx = fmaxf(mx, __shfl_xor(mx, 16, 64));  sm += __shfl_xor(sm, 16, 64);
    mx = fmaxf(mx, __shfl_xor(mx, 32, 64));  sm += __shfl_xor(sm, 32, 64);
    if (lane == 0)
        measure[(size_t)bh * L_ + i] = mx - sm * (1.0f / (float)L_);
}

// ---------------------------------------------------------------------------
// K2: top-NS per (b,h), register-resident.  Ties: lower index (lax.top_k).
// ---------------------------------------------------------------------------
__global__ __launch_bounds__(256) void topk_kernel(
    const float* __restrict__ measure, int* __restrict__ idxOut)
{
    __shared__ float wv[4]; __shared__ int wi[4];
    __shared__ float bvS;   __shared__ int biS;
    int bh = blockIdx.x, t = threadIdx.x;
    const float4* m4 = (const float4*)(measure + (size_t)bh * L_);
    float vals[8];
    float4 a = m4[t*2], b = m4[t*2 + 1];
    vals[0]=a.x; vals[1]=a.y; vals[2]=a.z; vals[3]=a.w;
    vals[4]=b.x; vals[5]=b.y; vals[6]=b.z; vals[7]=b.w;

    float lv = -FLT_MAX; int li = t*8;
    #pragma unroll
    for (int e = 0; e < 8; ++e) if (vals[e] > lv) { lv = vals[e]; li = t*8 + e; }

    int lane = t & 63, w = t >> 6;
    for (int r = 0; r < NS; ++r) {
        float v = lv; int idx = li;
        #pragma unroll
        for (int off = 32; off; off >>= 1) {
            float ov = __shfl_xor(v, off, 64);
            int   oi = __shfl_xor(idx, off, 64);
            if (ov > v || (ov == v && oi < idx)) { v = ov; idx = oi; }
        }
        if (lane == 0) { wv[w] = v; wi[w] = idx; }
        __syncthreads();
        if (t == 0) {
            float bv = wv[0]; int bi = wi[0];
            #pragma unroll
            for (int ww = 1; ww < 4; ++ww)
                if (wv[ww] > bv || (wv[ww] == bv && wi[ww] < bi)) { bv = wv[ww]; bi = wi[ww]; }
            bvS = bv; biS = bi;
            idxOut[bh * NS + r] = bi;
        }
        __syncthreads();
        int bi = biS;
        if ((bi >> 3) == t) {
            #pragma unroll
            for (int e = 0; e < 8; ++e) if ((bi & 7) == e) vals[e] = -FLT_MAX;
            lv = -FLT_MAX; li = t*8;
            #pragma unroll
            for (int e = 0; e < 8; ++e) if (vals[e] > lv) { lv = vals[e]; li = t*8 + e; }
        }
        __syncthreads();
    }
}

// ---------------------------------------------------------------------------
// K3: cumsum(v) along L, two passes, 1024 blocks each.
// ---------------------------------------------------------------------------
__global__ __launch_bounds__(256) void cumsum_p1(
    const float* __restrict__ v, float4* __restrict__ vpart)
{
    __shared__ float4 part[16][16];
    int bh = blockIdx.x >> 4, c = blockIdx.x & 15;
    int d4 = threadIdx.x & 15, sub = threadIdx.x >> 4;
    const float4* vb = (const float4*)(v + (size_t)bh * L_ * D_);
    int r0 = c*128 + sub*8;
    float4 s = make_float4(0,0,0,0);
    #pragma unroll
    for (int r = 0; r < 8; ++r) {
        float4 x = vb[(r0 + r)*16 + d4];
        s.x += x.x; s.y += x.y; s.z += x.z; s.w += x.w;
    }
    part[sub][d4] = s;
    __syncthreads();
    if (sub == 0) {
        float4 tot = part[0][d4];
        #pragma unroll
        for (int ss = 1; ss < 16; ++ss) {
            float4 x = part[ss][d4];
            tot.x += x.x; tot.y += x.y; tot.z += x.z; tot.w += x.w;
        }
        vpart[(bh*16 + c)*16 + d4] = tot;
    }
}

__global__ __launch_bounds__(256) void cumsum_p2(
    const float* __restrict__ v, const float4* __restrict__ vpart,
    float* __restrict__ out)
{
    __shared__ float4 part[16][16];
    int bh = blockIdx.x >> 4, c = blockIdx.x & 15;
    int d4 = threadIdx.x & 15, sub = threadIdx.x >> 4;
    const float4* vb = (const float4*)(v + (size_t)bh * L_ * D_);
    float4*       ob = (float4*)(out + (size_t)bh * L_ * D_);
    int r0 = c*128 + sub*8;
    float4 s = make_float4(0,0,0,0);
    #pragma unroll
    for (int r = 0; r < 8; ++r) {
        float4 x = vb[(r0 + r)*16 + d4];
        s.x += x.x; s.y += x.y; s.z += x.z; s.w += x.w;
    }
    part[sub][d4] = s;
    float4 run = make_float4(0,0,0,0);
    for (int cc = 0; cc < c; ++cc) {
        float4 x = vpart[(bh*16 + cc)*16 + d4];
        run.x += x.x; run.y += x.y; run.z += x.z; run.w += x.w;
    }
    __syncthreads();
    #pragma unroll
    for (int ss = 0; ss < 16; ++ss) {
        if (ss < sub) {
            float4 x = part[ss][d4];
            run.x += x.x; run.y += x.y; run.z += x.z; run.w += x.w;
        }
    }
    #pragma unroll
    for (int r = 0; r < 8; ++r) {
        float4 x = vb[(r0 + r)*16 + d4];
        run.x += x.x; run.y += x.y; run.z += x.z; run.w += x.w;
        ob[(r0 + r)*16 + d4] = run;
    }
}

// ---------------------------------------------------------------------------
// K4a: scores + softmax fused.  Block = (bh, group of 4 ranks), one wave per
// rank.  k staged per 128-row chunk in LDS (transposed f4 +1 pad).  Each
// wave keeps its full 2048-wide score row in 32 registers, does the masked
// softmax wave-locally, writes normalized weights once.
// ---------------------------------------------------------------------------
__global__ __launch_bounds__(256) void scores_kernel(
    const float* __restrict__ q, const float* __restrict__ k,
    const int* __restrict__ idxSel, float* __restrict__ attn)
{
    __shared__ float4 kbuf[16 * 129];   // [g][j], stride 129 f4
    int bh = blockIdx.x / 10, grp = blockIdx.x % 10;
    int qi = threadIdx.x >> 6, sub = threadIdx.x & 63;
    int rank = grp*4 + qi;
    int qrow = idxSel[bh*NS + rank];

    const float4* qrp = (const float4*)(q + ((size_t)bh * L_ + qrow) * D_);
    float4 qreg[16];
    #pragma unroll
    for (int g = 0; g < 16; ++g) qreg[g] = qrp[g];    // wave-uniform

    const float4* kb = (const float4*)(k + (size_t)bh * L_ * D_);
    float sc0[16], sc1[16];

    #pragma unroll
    for (int c = 0; c < 16; ++c) {
        __syncthreads();                               // kbuf reuse guard
        int j0 = c * 128;
        #pragma unroll
        for (int it = 0; it < 8; ++it) {               // coalesced stage
            int fi = threadIdx.x + 256*it;
            int g = fi & 15, j = fi >> 4;
            kbuf[g*129 + j] = kb[(size_t)(j0 + j)*16 + g];
        }
        __syncthreads();
        float acc0 = 0.f, acc1 = 0.f;
        #pragma unroll
        for (int g = 0; g < 16; ++g) {
            float4 k0 = kbuf[g*129 + sub];             // dense b128
            float4 k1 = kbuf[g*129 + sub + 64];
            float4 qq = qreg[g];
            acc0 += qq.x*k0.x + qq.y*k0.y + qq.z*k0.z + qq.w*k0.w;
            acc1 += qq.x*k1.x + qq.y*k1.y + qq.z*k1.z + qq.w*k1.w;
        }
        sc0[c] = acc0 * SCALE;
        sc1[c] = acc1 * SCALE;
    }

    // masked softmax, wave-local (row lives in sc0/sc1)
    float mx = -FLT_MAX;
    #pragma unroll
    for (int c = 0; c < 16; ++c) {
        if (c*128 + sub      <= qrow) mx = fmaxf(mx, sc0[c]);
        if (c*128 + sub + 64 <= qrow) mx = fmaxf(mx, sc1[c]);
    }
    #pragma unroll
    for (int off = 32; off; off >>= 1) mx = fmaxf(mx, __shfl_xor(mx, off, 64));

    float sum = 0.f;
    #pragma unroll
    for (int c = 0; c < 16; ++c) {
        sc0[c] = (c*128 + sub      <= qrow) ? __expf(sc0[c] - mx) : 0.f;
        sc1[c] = (c*128 + sub + 64 <= qrow) ? __expf(sc1[c] - mx) : 0.f;
        sum += sc0[c] + sc1[c];
    }
    #pragma unroll
    for (int off = 32; off; off >>= 1) sum += __shfl_xor(sum, off, 64);
    float inv = 1.f / sum;

    float* arow = attn + (size_t)(bh*NS + rank) * L_;
    #pragma unroll
    for (int c = 0; c < 16; ++c) {
        arow[c*128 + sub]      = sc0[c] * inv;         // coalesced
        arow[c*128 + sub + 64] = sc1[c] * inv;
    }
}

// ---------------------------------------------------------------------------
// K4b: out[bh, qrow, :] = attn_row @ v.
// ---------------------------------------------------------------------------
__global__ __launch_bounds__(256) void pv_kernel(
    const float* __restrict__ v, const int* __restrict__ idxSel,
    const float* __restrict__ attn, float* __restrict__ out)
{
    __shared__ float wl[L_ + 64];       // index j + 4*(j>>7)
    __shared__ float4 part[16][16];
    int bh = blockIdx.x / NS, r = blockIdx.x % NS;
    int qrow = idxSel[bh*NS + r];
    const float4* ar = (const float4*)(attn + (size_t)(bh*NS + r) * L_);
    int t = threadIdx.x;

    #pragma unroll
    for (int it = 0; it < 2; ++it) {
        int f = t + 256*it;
        float4 x = ar[f];
        int j = 4*f;
        *((float4*)&wl[j + 4*(j >> 7)]) = x;
    }
    __syncthreads();

    int d4 = t & 15, seg = t >> 4;
    const float4* vb = (const float4*)(v + (size_t)bh * L_ * D_);
    float4 acc = make_float4(0,0,0,0);
    int jlo = seg*128, jhi = min(jlo + 127, qrow);
    for (int j = jlo; j <= jhi; ++j) {
        float wgt = wl[j + 4*(j >> 7)];
        float4 x = vb[(size_t)j*16 + d4];
        acc.x += wgt*x.x; acc.y += wgt*x.y; acc.z += wgt*x.z; acc.w += wgt*x.w;
    }
    part[seg][d4] = acc;
    __syncthreads();
    for (int s2 = 8; s2; s2 >>= 1) {
        if (seg < s2) {
            float4 o = part[seg + s2][d4];
            acc.x += o.x; acc.y += o.y; acc.z += o.z; acc.w += o.w;
            part[seg][d4] = acc;
        }
        __syncthreads();
    }
    if (seg == 0) {
        float4* orow = (float4*)(out + ((size_t)bh * L_ + qrow) * D_);
        orow[d4] = acc;
    }
}

// ---------------------------------------------------------------------------
extern "C" void kernel_launch(void* const* d_in, const int* in_sizes, int n_in,
                              void* d_out, int out_size, void* d_ws, size_t ws_size,
                              hipStream_t stream) {
    const float* q    = (const float*)d_in[0];
    const float* k    = (const float*)d_in[1];
    const float* v    = (const float*)d_in[2];
    const int*   ridx = (const int*)d_in[3];

    float* out     = (float*)d_out;                    // (B,H,L,D)
    float* attnOut = out + (size_t)BH * L_ * D_;       // (B,H,NS,L)

    float*  measure = (float*)d_ws;                                          // BH*L floats
    int*    idxSel  = (int*)((char*)d_ws + (size_t)BH * L_ * sizeof(float)); // BH*NS ints
    float4* vpart   = (float4*)d_ws;   // aliases measure: only used AFTER topk

    measure_kernel<<<BH * L_ / 4, 256, 0, stream>>>(q, k, ridx, measure);
    topk_kernel   <<<BH,          256, 0, stream>>>(measure, idxSel);
    cumsum_p1     <<<BH * 16,     256, 0, stream>>>(v, vpart);
    cumsum_p2     <<<BH * 16,     256, 0, stream>>>(v, vpart, out);
    scores_kernel <<<BH * 10,     256, 0, stream>>>(q, k, idxSel, attnOut);
    pv_kernel     <<<BH * NS,     256, 0, stream>>>(v, idxSel, attnOut, out);
}